// Round 15
// baseline (232.586 us; speedup 1.0000x reference)
//
#include <hip/hip_runtime.h>
#include <hip/hip_bf16.h>

#define D_MODEL 1024
#define NUM_HEADS 16
#define D_K 64
#define BATCH 2
#define SEQ 2048

typedef __attribute__((ext_vector_type(8))) short bf16x8;
typedef __attribute__((ext_vector_type(4))) float f32x4;

union P16 { int4 i4; ushort u[8]; };
union FU { float f; unsigned int u; };

__device__ __forceinline__ float bf2f(ushort u) {
    union { unsigned int i; float f; } c; c.i = ((unsigned int)u) << 16; return c.f;
}
__device__ __forceinline__ ushort f2bf(float f) {
    union { float f; unsigned int i; } c; c.f = f;
    unsigned int x = c.i;
    return (ushort)((x + 0x7fff + ((x >> 16) & 1)) >> 16);
}

// per-wave inline dtype detect (every wave reads the same 64 values -> uniform)
__device__ __forceinline__ bool wave_detect_f32(const ushort* x) {
    ushort u = x[2 * (threadIdx.x & 63)];
    int e = (u >> 7) & 0xFF;
    unsigned long long bl = __ballot(e >= 100 && e <= 141);
    return __popcll(bl) < 32;
}

// ---------------- fused prep: detect + convert_x + both weight transposes ----------------
__global__ __launch_bounds__(256)
void prep_all(const ushort* __restrict__ x, const void* __restrict__ Wq,
              const void* __restrict__ Wo, ushort* __restrict__ xb,
              ushort* __restrict__ WqT, ushort* __restrict__ WoT,
              int* __restrict__ flag)
{
    const bool f32 = wave_detect_f32(x);
    const int bx = blockIdx.x, tx = threadIdx.x;
    if (bx == 0 && tx == 0) flag[0] = f32 ? 1 : 0;

    if (bx >= 1024) {               // convert x -> bf16 (fp32 inputs only)
        if (!f32) return;
        int i = ((bx - 1024) * 256 + tx) * 8;
        const float* f = (const float*)x + i;
        float4 a = *(const float4*)f, b = *(const float4*)(f + 4);
        P16 r;
        r.u[0] = f2bf(a.x); r.u[1] = f2bf(a.y); r.u[2] = f2bf(a.z); r.u[3] = f2bf(a.w);
        r.u[4] = f2bf(b.x); r.u[5] = f2bf(b.y); r.u[6] = f2bf(b.z); r.u[7] = f2bf(b.w);
        *(int4*)(xb + i) = r.i4;
        return;
    }

    __shared__ ushort t[64][72];
    const int nb = bx & 63, kb = bx >> 6;
    const void* W; ushort* WT; int N, n0;
    if (nb < 48) { W = Wq; WT = WqT; N = 3 * D_MODEL; n0 = nb * 64; }
    else         { W = Wo; WT = WoT; N = D_MODEL;     n0 = (nb - 48) * 64; }
    const int k0 = kb * 64, K = D_MODEL;
    #pragma unroll
    for (int p = 0; p < 16; ++p) {
        int r = p * 4 + (tx >> 6), c = tx & 63;
        float v = f32 ? ((const float*)W)[(size_t)(k0 + r) * N + n0 + c]
                      : bf2f(((const ushort*)W)[(size_t)(k0 + r) * N + n0 + c]);
        t[r][c] = f2bf(v);
    }
    __syncthreads();
    #pragma unroll
    for (int p = 0; p < 16; ++p) {
        int nn = p * 4 + (tx >> 6), kk = tx & 63;
        WT[(size_t)(n0 + nn) * K + k0 + kk] = t[kk][nn];
    }
}

// ---------------- GEMM v3 (kept from round 14: LDS dbuf, one barrier/iter) ----------------
template<int MODE>
__global__ __launch_bounds__(256)
void gemm128(const void* __restrict__ Araw, const ushort* __restrict__ Aconv,
             const ushort* __restrict__ WT, const void* __restrict__ bias,
             void* __restrict__ out, int N, int K, const int* __restrict__ flag)
{
    __shared__ ushort As[2][128 * 32];
    __shared__ ushort Bs[2][128 * 32];

    const int f = *flag;
    const ushort* A = (MODE == 1) ? (f ? Aconv : (const ushort*)Araw) : Aconv;

    const int tid = threadIdx.x;
    const int w = tid >> 6, lane = tid & 63;
    const int ln = lane & 15, quad = lane >> 4;
    const int m0 = blockIdx.y * 128, n0 = blockIdx.x * 128;
    const int wm = (w >> 1) * 64, wn = (w & 1) * 64;

    const int s0 = w * 128 + lane, s1 = s0 + 64;
    const int ar0 = s0 >> 2, ak0 = ((s0 & 3) ^ ((ar0 >> 1) & 3)) * 8;
    const int ar1 = s1 >> 2, ak1 = ((s1 & 3) ^ ((ar1 >> 1) & 3)) * 8;
    const size_t aoff0 = (size_t)(m0 + ar0) * K + ak0;
    const size_t aoff1 = (size_t)(m0 + ar1) * K + ak1;
    const size_t boff0 = (size_t)(n0 + ar0) * K + ak0;
    const size_t boff1 = (size_t)(n0 + ar1) * K + ak1;

    const int physc = (quad ^ ((ln >> 1) & 3)) * 8;

    f32x4 acc[4][4] = {};

    const int nk = K >> 5;
    int4 a0 = *(const int4*)(A + aoff0);
    int4 a1 = *(const int4*)(A + aoff1);
    int4 b0 = *(const int4*)(WT + boff0);
    int4 b1 = *(const int4*)(WT + boff1);
    *(int4*)(As[0] + s0 * 8) = a0;
    *(int4*)(As[0] + s1 * 8) = a1;
    *(int4*)(Bs[0] + s0 * 8) = b0;
    *(int4*)(Bs[0] + s1 * 8) = b1;
    a0 = *(const int4*)(A + aoff0 + 32);
    a1 = *(const int4*)(A + aoff1 + 32);
    b0 = *(const int4*)(WT + boff0 + 32);
    b1 = *(const int4*)(WT + boff1 + 32);
    __syncthreads();

    for (int kt = 0; kt < nk; ++kt) {
        const int cur = kt & 1;
        if (kt + 1 < nk) {
            *(int4*)(As[1 - cur] + s0 * 8) = a0;
            *(int4*)(As[1 - cur] + s1 * 8) = a1;
            *(int4*)(Bs[1 - cur] + s0 * 8) = b0;
            *(int4*)(Bs[1 - cur] + s1 * 8) = b1;
        }
        if (kt + 2 < nk) {
            const int kc = (kt + 2) * 32;
            a0 = *(const int4*)(A + aoff0 + kc);
            a1 = *(const int4*)(A + aoff1 + kc);
            b0 = *(const int4*)(WT + boff0 + kc);
            b1 = *(const int4*)(WT + boff1 + kc);
        }

        bf16x8 af[4], bf[4];
        #pragma unroll
        for (int t = 0; t < 4; ++t) {
            af[t] = *(const bf16x8*)(As[cur] + (wm + t * 16 + ln) * 32 + physc);
            bf[t] = *(const bf16x8*)(Bs[cur] + (wn + t * 16 + ln) * 32 + physc);
        }
        #pragma unroll
        for (int mi = 0; mi < 4; ++mi)
            #pragma unroll
            for (int ni = 0; ni < 4; ++ni)
                acc[mi][ni] = __builtin_amdgcn_mfma_f32_16x16x32_bf16(
                    af[mi], bf[ni], acc[mi][ni], 0, 0, 0);
        __syncthreads();
    }

    #pragma unroll
    for (int mi = 0; mi < 4; ++mi) {
        #pragma unroll
        for (int ni = 0; ni < 4; ++ni) {
            int col = n0 + wn + ni * 16 + ln;
            float bb = f ? ((const float*)bias)[col] : bf2f(((const ushort*)bias)[col]);
            #pragma unroll
            for (int r = 0; r < 4; ++r) {
                int row = m0 + wm + mi * 16 + quad * 4 + r;
                float v = acc[mi][ni][r] + bb;
                if (MODE == 0 && f) ((float*)out)[(size_t)row * N + col] = v;
                else                ((ushort*)out)[(size_t)row * N + col] = f2bf(v);
            }
        }
    }
}

// ---------------- MFMA flash attention v9: v7 schedule, 2 kv-tiles/interval ----------------
// v8's regression was LDS read/write arbitration (staging writes concurrent
// with MFMA frag reads). v9 keeps v7's fenced schedule -- barrier, write,
// barrier, compute -- but stages TWO tiles per interval into Ks/Vs[0/1]:
// barriers per tile halve (2->1) with writes still fenced away from reads.
// Prefetch for tiles jt+2/jt+3 issues after the second barrier: two compute
// phases of vmcnt slack.
__global__ __launch_bounds__(256)
void flash_attn9(const ushort* __restrict__ qkv, ushort* __restrict__ attn)
{
    __shared__ ushort Ks[2][64][72];
    __shared__ ushort Vs[2][64][72];
    __shared__ ushort QPs[128][72];  // [pg*64 + mt*32 + local]

    const int tid  = threadIdx.x;          // 256 thr, 4 waves
    const int wave = tid >> 6, lane = tid & 63;
    const int ln   = lane & 15, quad = lane >> 4;
    const int pg   = wave >> 1, ww = wave & 1;
    const int bh   = blockIdx.x;    // all blocks of a bh land on XCD bh%8
    const int ky   = blockIdx.y;
    const int k    = (ky < 8) ? ky : 23 - ky;
    const int xx   = 2 * k + pg;
    const int b    = bh >> 4, hh = bh & (NUM_HEADS - 1);
    const int W3   = 3 * D_MODEL;
    const size_t hbase = (size_t)b * SEQ * W3 + hh * D_K;

    const int q0A = 32 * (63 - xx), q0B = 32 * xx;
    const int ntA = 32 - k, ntB = k + 1;     // ntA in [17,32], same for both pg

    const int qrr = tid >> 1, qcol = (tid & 1) * 32;       // Q: 128 rows x 64
    const int ksr = tid >> 2, ksc = (tid & 3) * 16;        // K: 64 rows, 2 int4
    const int vp  = tid & 31, vg = (tid >> 5) * 8;         // V: 8 b32 each

    // stage both pairs' Q tiles (128 rows), scaled by 0.125*log2(e)
    {
        const int qpg = qrr >> 6, qmt = (qrr >> 5) & 1, ql = qrr & 31;
        const int qxx = 2 * k + qpg;
        const int grow = qmt ? (32 * qxx + ql) : (32 * (63 - qxx) + ql);
        const ushort* src = qkv + hbase + (size_t)grow * W3 + qcol;
        #pragma unroll
        for (int h = 0; h < 4; ++h) {
            P16 v; v.i4 = *(const int4*)(src + h * 8);
            #pragma unroll
            for (int e = 0; e < 8; ++e) v.u[e] = f2bf(bf2f(v.u[e]) * 0.18033688011f);
            *(int4*)(&QPs[qrr][qcol + h * 8]) = v.i4;
        }
    }

    const ushort* Kbase = qkv + hbase + D_MODEL;
    const ushort* Vbase = qkv + hbase + 2 * D_MODEL;

    // preload tiles 0 and 1 into regs (always valid: ntA >= 17)
    int4 kreg[2][2], vreg[2][2];
    #pragma unroll
    for (int u = 0; u < 2; ++u) {
        const int jr = u * 64;
        const ushort* ksrc = Kbase + (size_t)(jr + ksr) * W3 + ksc;
        kreg[u][0] = *(const int4*)(ksrc);
        kreg[u][1] = *(const int4*)(ksrc + 8);
        vreg[u][0] = *(const int4*)(Vbase + (size_t)(jr + 2 * vp)     * W3 + vg);
        vreg[u][1] = *(const int4*)(Vbase + (size_t)(jr + 2 * vp + 1) * W3 + vg);
    }
    __syncthreads();

    bf16x8 qf[2][2];
    #pragma unroll
    for (int mt = 0; mt < 2; ++mt)
        #pragma unroll
        for (int s = 0; s < 2; ++s)
            qf[mt][s] = *(const bf16x8*)(&QPs[pg * 64 + mt * 32 + ww * 16 + ln][s * 32 + quad * 8]);

    f32x4 acc_o[2][4] = {};
    f32x4 acc_l[2] = {};

    bf16x8 ones8;
    #pragma unroll
    for (int e = 0; e < 8; ++e) ones8[e] = (short)0x3F80;   // bf16 1.0

    for (int jt2 = 0; jt2 < ntA; jt2 += 2) {
        __syncthreads();   // prior interval's Ks/Vs reads done (fences writes)

        // write staged regs -> LDS (both tiles)
        #pragma unroll
        for (int u = 0; u < 2; ++u) {
            if (u && jt2 + 1 >= ntA) break;
            *(int4*)(&Ks[u][ksr][ksc])     = kreg[u][0];
            *(int4*)(&Ks[u][ksr][ksc + 8]) = kreg[u][1];
            P16 v0, v1; v0.i4 = vreg[u][0]; v1.i4 = vreg[u][1];
            #pragma unroll
            for (int e = 0; e < 8; ++e) {
                unsigned int pack = (unsigned int)v0.u[e] | ((unsigned int)v1.u[e] << 16);
                *(unsigned int*)(&Vs[u][vg + e][2 * vp]) = pack;
            }
        }
        __syncthreads();   // LDS visible; no writes during compute below

        // prefetch tiles jt2+2, jt2+3 (two compute phases of slack)
        #pragma unroll
        for (int u = 0; u < 2; ++u) {
            if (jt2 + 2 + u < ntA) {
                const int jr = (jt2 + 2 + u) * 64;
                const ushort* ksrc = Kbase + (size_t)(jr + ksr) * W3 + ksc;
                kreg[u][0] = *(const int4*)(ksrc);
                kreg[u][1] = *(const int4*)(ksrc + 8);
                vreg[u][0] = *(const int4*)(Vbase + (size_t)(jr + 2 * vp)     * W3 + vg);
                vreg[u][1] = *(const int4*)(Vbase + (size_t)(jr + 2 * vp + 1) * W3 + vg);
            }
        }

        // compute both tiles (exact v7 body, indexed by u)
        #pragma unroll
        for (int u = 0; u < 2; ++u) {
            const int jt = jt2 + u;
            if (u && jt >= ntA) break;
            const int j0 = jt * 64;
            const bool doB = (jt < ntB);

            f32x4 sa[2][4];
            #pragma unroll
            for (int t = 0; t < 4; ++t) {
                bf16x8 k0 = *(const bf16x8*)(&Ks[u][t * 16 + ln][quad * 8]);
                bf16x8 k1 = *(const bf16x8*)(&Ks[u][t * 16 + ln][32 + quad * 8]);
                {
                    f32x4 z = {};
                    z = __builtin_amdgcn_mfma_f32_16x16x32_bf16(qf[0][0], k0, z, 0, 0, 0);
                    z = __builtin_amdgcn_mfma_f32_16x16x32_bf16(qf[0][1], k1, z, 0, 0, 0);
                    sa[0][t] = z;
                }
                if (doB) {
                    f32x4 z = {};
                    z = __builtin_amdgcn_mfma_f32_16x16x32_bf16(qf[1][0], k0, z, 0, 0, 0);
                    z = __builtin_amdgcn_mfma_f32_16x16x32_bf16(qf[1][1], k1, z, 0, 0, 0);
                    sa[1][t] = z;
                }
            }

            if (jt == ntA - 1) {
                const int rowb = q0A + ww * 16 + quad * 4;
                #pragma unroll
                for (int t = 0; t < 4; ++t)
                    #pragma unroll
                    for (int r = 0; r < 4; ++r)
                        if (j0 + t * 16 + ln > rowb + r) sa[0][t][r] = -1e30f;
            }
            if (doB && jt == ntB - 1) {
                const int rowb = q0B + ww * 16 + quad * 4;
                #pragma unroll
                for (int t = 0; t < 4; ++t)
                    #pragma unroll
                    for (int r = 0; r < 4; ++r)
                        if (j0 + t * 16 + ln > rowb + r) sa[1][t][r] = -1e30f;
            }

            const int lnx = ln ^ ((quad & 1) * 8);
            #pragma unroll
            for (int mt = 0; mt < 2; ++mt) {
                if (mt && !doB) break;
                #pragma unroll
                for (int r = 0; r < 4; ++r) {
                    const int prow = pg * 64 + mt * 32 + ww * 16 + quad * 4 + r;
                    #pragma unroll
                    for (int t = 0; t < 4; ++t) {
                        FU cc; cc.f = exp2f(sa[mt][t][r]);
                        QPs[prow][((t ^ (quad >> 1)) * 16) + lnx] = (ushort)(cc.u >> 16);
                    }
                }
            }

            #pragma unroll
            for (int s = 0; s < 2; ++s) {
                const int pcol = s * 32 + ((quad ^ ((ln >> 2) & 3)) * 8);
                bf16x8 pf0 = *(const bf16x8*)(&QPs[pg * 64 + ww * 16 + ln][pcol]);
                bf16x8 pf1;
                if (doB) pf1 = *(const bf16x8*)(&QPs[pg * 64 + 32 + ww * 16 + ln][pcol]);
                #pragma unroll
                for (int t = 0; t < 4; ++t) {
                    bf16x8 vf = *(const bf16x8*)(&Vs[u][t * 16 + ln][s * 32 + quad * 8]);
                    acc_o[0][t] = __builtin_amdgcn_mfma_f32_16x16x32_bf16(pf0, vf, acc_o[0][t], 0, 0, 0);
                    if (doB)
                        acc_o[1][t] = __builtin_amdgcn_mfma_f32_16x16x32_bf16(pf1, vf, acc_o[1][t], 0, 0, 0);
                }
                acc_l[0] = __builtin_amdgcn_mfma_f32_16x16x32_bf16(pf0, ones8, acc_l[0], 0, 0, 0);
                if (doB)
                    acc_l[1] = __builtin_amdgcn_mfma_f32_16x16x32_bf16(pf1, ones8, acc_l[1], 0, 0, 0);
            }
        }
    }

    // epilogue: normalize, write [B,S,H*64+dk]
    #pragma unroll
    for (int mt = 0; mt < 2; ++mt) {
        const int q0 = mt ? q0B : q0A;
        #pragma unroll
        for (int r = 0; r < 4; ++r) {
            float inv = 1.0f / acc_l[mt][r];
            int i = q0 + ww * 16 + quad * 4 + r;
            size_t rowoff = ((size_t)(b * SEQ + i)) * D_MODEL + hh * D_K;
            #pragma unroll
            for (int t = 0; t < 4; ++t)
                attn[rowoff + t * 16 + ln] = f2bf(acc_o[mt][t][r] * inv);
        }
    }
}

extern "C" void kernel_launch(void* const* d_in, const int* in_sizes, int n_in,
                              void* d_out, int out_size, void* d_ws, size_t ws_size,
                              hipStream_t stream)
{
    const void* x     = d_in[0];
    // d_in[1] = int32 tril mask -- causal handled analytically
    const void* w_qkv = d_in[2];
    const void* b_qkv = d_in[3];
    const void* w_out = d_in[4];
    const void* b_out = d_in[5];

    char* ws = (char*)d_ws;
    int*    flag   = (int*)ws;                  size_t off = 256;
    ushort* WqkvT  = (ushort*)(ws + off);       off += (size_t)3 * D_MODEL * D_MODEL * 2;
    ushort* WoutT  = (ushort*)(ws + off);       off += (size_t)D_MODEL * D_MODEL * 2;
    ushort* qkv_ws = (ushort*)(ws + off);       off += (size_t)BATCH * SEQ * 3 * D_MODEL * 2;
    ushort* xb     = (ushort*)(ws + off);       // aliases attn_ws: xb dead after QKV gemm
    ushort* attn_ws = xb;

    const int M = BATCH * SEQ;          // 4096

    prep_all<<<3072, 256, 0, stream>>>((const ushort*)x, w_qkv, w_out,
                                       xb, WqkvT, WoutT, flag);

    gemm128<1><<<dim3(3 * D_MODEL / 128, M / 128), 256, 0, stream>>>(
        x, xb, WqkvT, b_qkv, qkv_ws, 3 * D_MODEL, D_MODEL, flag);

    dim3 ga(BATCH * NUM_HEADS, 16);   // x = bh (XCD locality), y = ky
    flash_attn9<<<ga, 256, 0, stream>>>(qkv_ws, attn_ws);

    gemm128<0><<<dim3(D_MODEL / 128, M / 128), 256, 0, stream>>>(
        attn_ws, attn_ws, WoutT, b_out, d_out, D_MODEL, D_MODEL, flag);
}

// Round 16
// 224.688 us; speedup vs baseline: 1.0352x; 1.0352x over previous
//
#include <hip/hip_runtime.h>
#include <hip/hip_bf16.h>

#define D_MODEL 1024
#define NUM_HEADS 16
#define D_K 64
#define BATCH 2
#define SEQ 2048

typedef __attribute__((ext_vector_type(8))) short bf16x8;
typedef __attribute__((ext_vector_type(4))) float f32x4;

union P16 { int4 i4; ushort u[8]; };
union FU { float f; unsigned int u; };

__device__ __forceinline__ float bf2f(ushort u) {
    union { unsigned int i; float f; } c; c.i = ((unsigned int)u) << 16; return c.f;
}
__device__ __forceinline__ ushort f2bf(float f) {
    union { float f; unsigned int i; } c; c.f = f;
    unsigned int x = c.i;
    return (ushort)((x + 0x7fff + ((x >> 16) & 1)) >> 16);
}

// per-wave inline dtype detect (every wave reads the same 64 values -> uniform)
__device__ __forceinline__ bool wave_detect_f32(const ushort* x) {
    ushort u = x[2 * (threadIdx.x & 63)];
    int e = (u >> 7) & 0xFF;
    unsigned long long bl = __ballot(e >= 100 && e <= 141);
    return __popcll(bl) < 32;
}

// ---------------- fused prep: detect + convert_x + both weight transposes ----------------
__global__ __launch_bounds__(256)
void prep_all(const ushort* __restrict__ x, const void* __restrict__ Wq,
              const void* __restrict__ Wo, ushort* __restrict__ xb,
              ushort* __restrict__ WqT, ushort* __restrict__ WoT,
              int* __restrict__ flag)
{
    const bool f32 = wave_detect_f32(x);
    const int bx = blockIdx.x, tx = threadIdx.x;
    if (bx == 0 && tx == 0) flag[0] = f32 ? 1 : 0;

    if (bx >= 1024) {               // convert x -> bf16 (fp32 inputs only)
        if (!f32) return;
        int i = ((bx - 1024) * 256 + tx) * 8;
        const float* f = (const float*)x + i;
        float4 a = *(const float4*)f, b = *(const float4*)(f + 4);
        P16 r;
        r.u[0] = f2bf(a.x); r.u[1] = f2bf(a.y); r.u[2] = f2bf(a.z); r.u[3] = f2bf(a.w);
        r.u[4] = f2bf(b.x); r.u[5] = f2bf(b.y); r.u[6] = f2bf(b.z); r.u[7] = f2bf(b.w);
        *(int4*)(xb + i) = r.i4;
        return;
    }

    __shared__ ushort t[64][72];
    const int nb = bx & 63, kb = bx >> 6;
    const void* W; ushort* WT; int N, n0;
    if (nb < 48) { W = Wq; WT = WqT; N = 3 * D_MODEL; n0 = nb * 64; }
    else         { W = Wo; WT = WoT; N = D_MODEL;     n0 = (nb - 48) * 64; }
    const int k0 = kb * 64, K = D_MODEL;
    #pragma unroll
    for (int p = 0; p < 16; ++p) {
        int r = p * 4 + (tx >> 6), c = tx & 63;
        float v = f32 ? ((const float*)W)[(size_t)(k0 + r) * N + n0 + c]
                      : bf2f(((const ushort*)W)[(size_t)(k0 + r) * N + n0 + c]);
        t[r][c] = f2bf(v);
    }
    __syncthreads();
    #pragma unroll
    for (int p = 0; p < 16; ++p) {
        int nn = p * 4 + (tx >> 6), kk = tx & 63;
        WT[(size_t)(n0 + nn) * K + k0 + kk] = t[kk][nn];
    }
}

// ---------------- GEMM v4: 64x128 tile, LDS dbuf, one barrier/iter ----------------
// Same verified XOR-swizzled LDS image and frag-read formulas as the 128-tile
// kernel; tile shrunk to 64 rows so g1 gets 1536 blocks (6/CU) and g0 512
// (2/CU) -- double the co-resident blocks for latency hiding (LDS 24 KB).
// Wave w owns all 64 m-rows x cols [w*32, w*32+32): 4x2 C-tiles, 6 ds_read +
// 8 MFMA per iter.
// MODE 1: A = flag ? Aconv : Araw(bf16); out bf16 [row][N].
// MODE 0: A = Aconv; out dtype per flag, [row][N].
template<int MODE>
__global__ __launch_bounds__(256)
void gemm64(const void* __restrict__ Araw, const ushort* __restrict__ Aconv,
            const ushort* __restrict__ WT, const void* __restrict__ bias,
            void* __restrict__ out, int N, int K, const int* __restrict__ flag)
{
    __shared__ ushort As[2][64 * 32];    // 8 KB
    __shared__ ushort Bs[2][128 * 32];   // 16 KB

    const int f = *flag;
    const ushort* A = (MODE == 1) ? (f ? Aconv : (const ushort*)Araw) : Aconv;

    const int tid = threadIdx.x;
    const int w = tid >> 6, lane = tid & 63;
    const int ln = lane & 15, quad = lane >> 4;
    const int m0 = blockIdx.y * 64, n0 = blockIdx.x * 128;
    const int wn = w * 32;

    // A: 256 chunks (64 rows x 4), thread t -> slot t.
    const int sa = tid;
    const int arow = sa >> 2, akc = ((sa & 3) ^ ((arow >> 1) & 3)) * 8;
    const size_t aoff = (size_t)(m0 + arow) * K + akc;
    // B: 512 chunks (128 rows x 4), slots t and t+256.
    const int sb0 = tid, sb1 = tid + 256;
    const int br0 = sb0 >> 2, bk0 = ((sb0 & 3) ^ ((br0 >> 1) & 3)) * 8;
    const int br1 = sb1 >> 2, bk1 = ((sb1 & 3) ^ ((br1 >> 1) & 3)) * 8;
    const size_t boff0 = (size_t)(n0 + br0) * K + bk0;
    const size_t boff1 = (size_t)(n0 + br1) * K + bk1;

    const int physc = (quad ^ ((ln >> 1) & 3)) * 8;

    f32x4 acc[4][2] = {};

    const int nk = K >> 5;                 // 32 iters at K=1024
    // k-tile 0 -> buf0
    int4 a0 = *(const int4*)(A + aoff);
    int4 b0 = *(const int4*)(WT + boff0);
    int4 b1 = *(const int4*)(WT + boff1);
    *(int4*)(As[0] + sa * 8)  = a0;
    *(int4*)(Bs[0] + sb0 * 8) = b0;
    *(int4*)(Bs[0] + sb1 * 8) = b1;
    // k-tile 1 -> regs
    a0 = *(const int4*)(A + aoff + 32);
    b0 = *(const int4*)(WT + boff0 + 32);
    b1 = *(const int4*)(WT + boff1 + 32);
    __syncthreads();

    for (int kt = 0; kt < nk; ++kt) {
        const int cur = kt & 1;
        if (kt + 1 < nk) {                 // buf[1-cur] last read at kt-1: safe
            *(int4*)(As[1 - cur] + sa * 8)  = a0;
            *(int4*)(Bs[1 - cur] + sb0 * 8) = b0;
            *(int4*)(Bs[1 - cur] + sb1 * 8) = b1;
        }
        if (kt + 2 < nk) {                 // loads get a full compute of slack
            const int kc = (kt + 2) * 32;
            a0 = *(const int4*)(A + aoff + kc);
            b0 = *(const int4*)(WT + boff0 + kc);
            b1 = *(const int4*)(WT + boff1 + kc);
        }

        bf16x8 af[4], bf[2];
        #pragma unroll
        for (int t = 0; t < 4; ++t)
            af[t] = *(const bf16x8*)(As[cur] + (t * 16 + ln) * 32 + physc);
        #pragma unroll
        for (int t = 0; t < 2; ++t)
            bf[t] = *(const bf16x8*)(Bs[cur] + (wn + t * 16 + ln) * 32 + physc);
        #pragma unroll
        for (int mi = 0; mi < 4; ++mi)
            #pragma unroll
            for (int ni = 0; ni < 2; ++ni)
                acc[mi][ni] = __builtin_amdgcn_mfma_f32_16x16x32_bf16(
                    af[mi], bf[ni], acc[mi][ni], 0, 0, 0);
        __syncthreads();                   // single barrier per iter
    }

    #pragma unroll
    for (int mi = 0; mi < 4; ++mi) {
        #pragma unroll
        for (int ni = 0; ni < 2; ++ni) {
            int col = n0 + wn + ni * 16 + ln;
            float bb = f ? ((const float*)bias)[col] : bf2f(((const ushort*)bias)[col]);
            #pragma unroll
            for (int r = 0; r < 4; ++r) {
                int row = m0 + mi * 16 + quad * 4 + r;
                float v = acc[mi][ni][r] + bb;
                if (MODE == 0 && f) ((float*)out)[(size_t)row * N + col] = v;
                else                ((ushort*)out)[(size_t)row * N + col] = f2bf(v);
            }
        }
    }
}

// ---------------- MFMA flash attention v7 (verbatim revert: 69.9 us known-good) ----------------
// v8 (LDS dbuf) and v9 (2-tile intervals) both regressed to ~88 us at 63-71 KB
// LDS; the 36 KB 2-barrier loop is the measured local optimum.
__global__ __launch_bounds__(256)
void flash_attn7(const ushort* __restrict__ qkv, ushort* __restrict__ attn)
{
    __shared__ ushort Ks[64][72];
    __shared__ ushort Vs[64][72];
    __shared__ ushort QPs[128][72];  // [pg*64 + mt*32 + local]

    const int tid  = threadIdx.x;          // 256 thr, 4 waves
    const int wave = tid >> 6, lane = tid & 63;
    const int ln   = lane & 15, quad = lane >> 4;
    const int pg   = wave >> 1, ww = wave & 1;
    const int bh   = blockIdx.x;    // all blocks of a bh land on XCD bh%8
    const int ky   = blockIdx.y;
    const int k    = (ky < 8) ? ky : 23 - ky;
    const int xx   = 2 * k + pg;
    const int b    = bh >> 4, hh = bh & (NUM_HEADS - 1);
    const int W3   = 3 * D_MODEL;
    const size_t hbase = (size_t)b * SEQ * W3 + hh * D_K;

    const int q0A = 32 * (63 - xx), q0B = 32 * xx;
    const int ntA = 32 - k, ntB = k + 1;     // identical for both pg

    const int qrr = tid >> 1, qcol = (tid & 1) * 32;       // Q: 128 rows x 64
    const int ksr = tid >> 2, ksc = (tid & 3) * 16;        // K: 64 rows, 2 int4
    const int vp  = tid & 31, vg = (tid >> 5) * 8;         // V: 8 b32 each

    // stage both pairs' Q tiles (128 rows), scaled by 0.125*log2(e)
    {
        const int qpg = qrr >> 6, qmt = (qrr >> 5) & 1, ql = qrr & 31;
        const int qxx = 2 * k + qpg;
        const int grow = qmt ? (32 * qxx + ql) : (32 * (63 - qxx) + ql);
        const ushort* src = qkv + hbase + (size_t)grow * W3 + qcol;
        #pragma unroll
        for (int h = 0; h < 4; ++h) {
            P16 v; v.i4 = *(const int4*)(src + h * 8);
            #pragma unroll
            for (int e = 0; e < 8; ++e) v.u[e] = f2bf(bf2f(v.u[e]) * 0.18033688011f);
            *(int4*)(&QPs[qrr][qcol + h * 8]) = v.i4;
        }
    }
    __syncthreads();
    bf16x8 qf[2][2];
    #pragma unroll
    for (int mt = 0; mt < 2; ++mt)
        #pragma unroll
        for (int s = 0; s < 2; ++s)
            qf[mt][s] = *(const bf16x8*)(&QPs[pg * 64 + mt * 32 + ww * 16 + ln][s * 32 + quad * 8]);

    f32x4 acc_o[2][4] = {};
    f32x4 acc_l[2] = {};

    bf16x8 ones8;
    #pragma unroll
    for (int e = 0; e < 8; ++e) ones8[e] = (short)0x3F80;   // bf16 1.0

    const ushort* Kbase = qkv + hbase + D_MODEL;
    const ushort* Vbase = qkv + hbase + 2 * D_MODEL;

    int4 kreg[2], vreg[2];
    {
        const ushort* ksrc = Kbase + (size_t)ksr * W3 + ksc;
        kreg[0] = *(const int4*)(ksrc);
        kreg[1] = *(const int4*)(ksrc + 8);
        vreg[0] = *(const int4*)(Vbase + (size_t)(2 * vp)     * W3 + vg);
        vreg[1] = *(const int4*)(Vbase + (size_t)(2 * vp + 1) * W3 + vg);
    }

    for (int jt = 0; jt < ntA; ++jt) {
        const int j0 = jt * 64;
        const bool doB = (jt < ntB);
        __syncthreads();

        *(int4*)(&Ks[ksr][ksc])     = kreg[0];
        *(int4*)(&Ks[ksr][ksc + 8]) = kreg[1];
        {
            P16 v0, v1; v0.i4 = vreg[0]; v1.i4 = vreg[1];
            #pragma unroll
            for (int e = 0; e < 8; ++e) {
                unsigned int pack = (unsigned int)v0.u[e] | ((unsigned int)v1.u[e] << 16);
                *(unsigned int*)(&Vs[vg + e][2 * vp]) = pack;
            }
        }
        __syncthreads();

        if (jt + 1 < ntA) {
            const int jn = j0 + 64;
            const ushort* ksrc = Kbase + (size_t)(jn + ksr) * W3 + ksc;
            kreg[0] = *(const int4*)(ksrc);
            kreg[1] = *(const int4*)(ksrc + 8);
            vreg[0] = *(const int4*)(Vbase + (size_t)(jn + 2 * vp)     * W3 + vg);
            vreg[1] = *(const int4*)(Vbase + (size_t)(jn + 2 * vp + 1) * W3 + vg);
        }

        f32x4 sa[2][4];
        #pragma unroll
        for (int t = 0; t < 4; ++t) {
            bf16x8 k0 = *(const bf16x8*)(&Ks[t * 16 + ln][quad * 8]);
            bf16x8 k1 = *(const bf16x8*)(&Ks[t * 16 + ln][32 + quad * 8]);
            {
                f32x4 z = {};
                z = __builtin_amdgcn_mfma_f32_16x16x32_bf16(qf[0][0], k0, z, 0, 0, 0);
                z = __builtin_amdgcn_mfma_f32_16x16x32_bf16(qf[0][1], k1, z, 0, 0, 0);
                sa[0][t] = z;
            }
            if (doB) {
                f32x4 z = {};
                z = __builtin_amdgcn_mfma_f32_16x16x32_bf16(qf[1][0], k0, z, 0, 0, 0);
                z = __builtin_amdgcn_mfma_f32_16x16x32_bf16(qf[1][1], k1, z, 0, 0, 0);
                sa[1][t] = z;
            }
        }

        if (jt == ntA - 1) {
            const int rowb = q0A + ww * 16 + quad * 4;
            #pragma unroll
            for (int t = 0; t < 4; ++t)
                #pragma unroll
                for (int r = 0; r < 4; ++r)
                    if (j0 + t * 16 + ln > rowb + r) sa[0][t][r] = -1e30f;
        }
        if (doB && jt == ntB - 1) {
            const int rowb = q0B + ww * 16 + quad * 4;
            #pragma unroll
            for (int t = 0; t < 4; ++t)
                #pragma unroll
                for (int r = 0; r < 4; ++r)
                    if (j0 + t * 16 + ln > rowb + r) sa[1][t][r] = -1e30f;
        }

        const int lnx = ln ^ ((quad & 1) * 8);
        #pragma unroll
        for (int mt = 0; mt < 2; ++mt) {
            if (mt && !doB) break;
            #pragma unroll
            for (int r = 0; r < 4; ++r) {
                const int prow = pg * 64 + mt * 32 + ww * 16 + quad * 4 + r;
                #pragma unroll
                for (int t = 0; t < 4; ++t) {
                    FU cc; cc.f = exp2f(sa[mt][t][r]);
                    QPs[prow][((t ^ (quad >> 1)) * 16) + lnx] = (ushort)(cc.u >> 16);
                }
            }
        }

        #pragma unroll
        for (int s = 0; s < 2; ++s) {
            const int pcol = s * 32 + ((quad ^ ((ln >> 2) & 3)) * 8);
            bf16x8 pf0 = *(const bf16x8*)(&QPs[pg * 64 + ww * 16 + ln][pcol]);
            bf16x8 pf1;
            if (doB) pf1 = *(const bf16x8*)(&QPs[pg * 64 + 32 + ww * 16 + ln][pcol]);
            #pragma unroll
            for (int t = 0; t < 4; ++t) {
                bf16x8 vf = *(const bf16x8*)(&Vs[t * 16 + ln][s * 32 + quad * 8]);
                acc_o[0][t] = __builtin_amdgcn_mfma_f32_16x16x32_bf16(pf0, vf, acc_o[0][t], 0, 0, 0);
                if (doB)
                    acc_o[1][t] = __builtin_amdgcn_mfma_f32_16x16x32_bf16(pf1, vf, acc_o[1][t], 0, 0, 0);
            }
            acc_l[0] = __builtin_amdgcn_mfma_f32_16x16x32_bf16(pf0, ones8, acc_l[0], 0, 0, 0);
            if (doB)
                acc_l[1] = __builtin_amdgcn_mfma_f32_16x16x32_bf16(pf1, ones8, acc_l[1], 0, 0, 0);
        }
    }

    #pragma unroll
    for (int mt = 0; mt < 2; ++mt) {
        const int q0 = mt ? q0B : q0A;
        #pragma unroll
        for (int r = 0; r < 4; ++r) {
            float inv = 1.0f / acc_l[mt][r];
            int i = q0 + ww * 16 + quad * 4 + r;
            size_t rowoff = ((size_t)(b * SEQ + i)) * D_MODEL + hh * D_K;
            #pragma unroll
            for (int t = 0; t < 4; ++t)
                attn[rowoff + t * 16 + ln] = f2bf(acc_o[mt][t][r] * inv);
        }
    }
}

extern "C" void kernel_launch(void* const* d_in, const int* in_sizes, int n_in,
                              void* d_out, int out_size, void* d_ws, size_t ws_size,
                              hipStream_t stream)
{
    const void* x     = d_in[0];
    // d_in[1] = int32 tril mask -- causal handled analytically
    const void* w_qkv = d_in[2];
    const void* b_qkv = d_in[3];
    const void* w_out = d_in[4];
    const void* b_out = d_in[5];

    char* ws = (char*)d_ws;
    int*    flag   = (int*)ws;                  size_t off = 256;
    ushort* WqkvT  = (ushort*)(ws + off);       off += (size_t)3 * D_MODEL * D_MODEL * 2;
    ushort* WoutT  = (ushort*)(ws + off);       off += (size_t)D_MODEL * D_MODEL * 2;
    ushort* qkv_ws = (ushort*)(ws + off);       off += (size_t)BATCH * SEQ * 3 * D_MODEL * 2;
    ushort* xb     = (ushort*)(ws + off);       // aliases attn_ws: xb dead after QKV gemm
    ushort* attn_ws = xb;

    const int M = BATCH * SEQ;          // 4096

    prep_all<<<3072, 256, 0, stream>>>((const ushort*)x, w_qkv, w_out,
                                       xb, WqkvT, WoutT, flag);

    gemm64<1><<<dim3(3 * D_MODEL / 128, M / 64), 256, 0, stream>>>(
        x, xb, WqkvT, b_qkv, qkv_ws, 3 * D_MODEL, D_MODEL, flag);

    dim3 ga(BATCH * NUM_HEADS, 16);   // x = bh (XCD locality), y = ky
    flash_attn7<<<ga, 256, 0, stream>>>(qkv_ws, attn_ws);

    gemm64<0><<<dim3(D_MODEL / 128, M / 64), 256, 0, stream>>>(
        attn_ws, attn_ws, WoutT, b_out, d_out, D_MODEL, D_MODEL, flag);
}

// Round 17
// 214.724 us; speedup vs baseline: 1.0832x; 1.0464x over previous
//
#include <hip/hip_runtime.h>
#include <hip/hip_bf16.h>

#define D_MODEL 1024
#define NUM_HEADS 16
#define D_K 64
#define BATCH 2
#define SEQ 2048

typedef __attribute__((ext_vector_type(8))) short bf16x8;
typedef __attribute__((ext_vector_type(4))) float f32x4;

union P16 { int4 i4; ushort u[8]; };
union FU { float f; unsigned int u; };

__device__ __forceinline__ float bf2f(ushort u) {
    union { unsigned int i; float f; } c; c.i = ((unsigned int)u) << 16; return c.f;
}
__device__ __forceinline__ ushort f2bf(float f) {
    union { float f; unsigned int i; } c; c.f = f;
    unsigned int x = c.i;
    return (ushort)((x + 0x7fff + ((x >> 16) & 1)) >> 16);
}

// per-wave inline dtype detect (every wave reads the same 64 values -> uniform)
__device__ __forceinline__ bool wave_detect_f32(const ushort* x) {
    ushort u = x[2 * (threadIdx.x & 63)];
    int e = (u >> 7) & 0xFF;
    unsigned long long bl = __ballot(e >= 100 && e <= 141);
    return __popcll(bl) < 32;
}

// ---------------- fused prep: detect + convert_x + both weight transposes ----------------
__global__ __launch_bounds__(256)
void prep_all(const ushort* __restrict__ x, const void* __restrict__ Wq,
              const void* __restrict__ Wo, ushort* __restrict__ xb,
              ushort* __restrict__ WqT, ushort* __restrict__ WoT,
              int* __restrict__ flag)
{
    const bool f32 = wave_detect_f32(x);
    const int bx = blockIdx.x, tx = threadIdx.x;
    if (bx == 0 && tx == 0) flag[0] = f32 ? 1 : 0;

    if (bx >= 1024) {               // convert x -> bf16 (fp32 inputs only)
        if (!f32) return;
        int i = ((bx - 1024) * 256 + tx) * 8;
        const float* f = (const float*)x + i;
        float4 a = *(const float4*)f, b = *(const float4*)(f + 4);
        P16 r;
        r.u[0] = f2bf(a.x); r.u[1] = f2bf(a.y); r.u[2] = f2bf(a.z); r.u[3] = f2bf(a.w);
        r.u[4] = f2bf(b.x); r.u[5] = f2bf(b.y); r.u[6] = f2bf(b.z); r.u[7] = f2bf(b.w);
        *(int4*)(xb + i) = r.i4;
        return;
    }

    __shared__ ushort t[64][72];
    const int nb = bx & 63, kb = bx >> 6;
    const void* W; ushort* WT; int N, n0;
    if (nb < 48) { W = Wq; WT = WqT; N = 3 * D_MODEL; n0 = nb * 64; }
    else         { W = Wo; WT = WoT; N = D_MODEL;     n0 = (nb - 48) * 64; }
    const int k0 = kb * 64, K = D_MODEL;
    #pragma unroll
    for (int p = 0; p < 16; ++p) {
        int r = p * 4 + (tx >> 6), c = tx & 63;
        float v = f32 ? ((const float*)W)[(size_t)(k0 + r) * N + n0 + c]
                      : bf2f(((const ushort*)W)[(size_t)(k0 + r) * N + n0 + c]);
        t[r][c] = f2bf(v);
    }
    __syncthreads();
    #pragma unroll
    for (int p = 0; p < 16; ++p) {
        int nn = p * 4 + (tx >> 6), kk = tx & 63;
        WT[(size_t)(n0 + nn) * K + k0 + kk] = t[kk][nn];
    }
}

// ---------------- GEMM 128x128 v3 (best measured: LDS dbuf, one barrier/iter) ----------------
// Used for the FLOP-heavy QKV gemm (768 blocks, 3/CU).
template<int MODE>
__global__ __launch_bounds__(256)
void gemm128(const void* __restrict__ Araw, const ushort* __restrict__ Aconv,
             const ushort* __restrict__ WT, const void* __restrict__ bias,
             void* __restrict__ out, int N, int K, const int* __restrict__ flag)
{
    __shared__ ushort As[2][128 * 32];
    __shared__ ushort Bs[2][128 * 32];

    const int f = *flag;
    const ushort* A = (MODE == 1) ? (f ? Aconv : (const ushort*)Araw) : Aconv;

    const int tid = threadIdx.x;
    const int w = tid >> 6, lane = tid & 63;
    const int ln = lane & 15, quad = lane >> 4;
    const int m0 = blockIdx.y * 128, n0 = blockIdx.x * 128;
    const int wm = (w >> 1) * 64, wn = (w & 1) * 64;

    const int s0 = w * 128 + lane, s1 = s0 + 64;
    const int ar0 = s0 >> 2, ak0 = ((s0 & 3) ^ ((ar0 >> 1) & 3)) * 8;
    const int ar1 = s1 >> 2, ak1 = ((s1 & 3) ^ ((ar1 >> 1) & 3)) * 8;
    const size_t aoff0 = (size_t)(m0 + ar0) * K + ak0;
    const size_t aoff1 = (size_t)(m0 + ar1) * K + ak1;
    const size_t boff0 = (size_t)(n0 + ar0) * K + ak0;
    const size_t boff1 = (size_t)(n0 + ar1) * K + ak1;

    const int physc = (quad ^ ((ln >> 1) & 3)) * 8;

    f32x4 acc[4][4] = {};

    const int nk = K >> 5;
    int4 a0 = *(const int4*)(A + aoff0);
    int4 a1 = *(const int4*)(A + aoff1);
    int4 b0 = *(const int4*)(WT + boff0);
    int4 b1 = *(const int4*)(WT + boff1);
    *(int4*)(As[0] + s0 * 8) = a0;
    *(int4*)(As[0] + s1 * 8) = a1;
    *(int4*)(Bs[0] + s0 * 8) = b0;
    *(int4*)(Bs[0] + s1 * 8) = b1;
    a0 = *(const int4*)(A + aoff0 + 32);
    a1 = *(const int4*)(A + aoff1 + 32);
    b0 = *(const int4*)(WT + boff0 + 32);
    b1 = *(const int4*)(WT + boff1 + 32);
    __syncthreads();

    for (int kt = 0; kt < nk; ++kt) {
        const int cur = kt & 1;
        if (kt + 1 < nk) {
            *(int4*)(As[1 - cur] + s0 * 8) = a0;
            *(int4*)(As[1 - cur] + s1 * 8) = a1;
            *(int4*)(Bs[1 - cur] + s0 * 8) = b0;
            *(int4*)(Bs[1 - cur] + s1 * 8) = b1;
        }
        if (kt + 2 < nk) {
            const int kc = (kt + 2) * 32;
            a0 = *(const int4*)(A + aoff0 + kc);
            a1 = *(const int4*)(A + aoff1 + kc);
            b0 = *(const int4*)(WT + boff0 + kc);
            b1 = *(const int4*)(WT + boff1 + kc);
        }

        bf16x8 af[4], bf[4];
        #pragma unroll
        for (int t = 0; t < 4; ++t) {
            af[t] = *(const bf16x8*)(As[cur] + (wm + t * 16 + ln) * 32 + physc);
            bf[t] = *(const bf16x8*)(Bs[cur] + (wn + t * 16 + ln) * 32 + physc);
        }
        #pragma unroll
        for (int mi = 0; mi < 4; ++mi)
            #pragma unroll
            for (int ni = 0; ni < 4; ++ni)
                acc[mi][ni] = __builtin_amdgcn_mfma_f32_16x16x32_bf16(
                    af[mi], bf[ni], acc[mi][ni], 0, 0, 0);
        __syncthreads();
    }

    #pragma unroll
    for (int mi = 0; mi < 4; ++mi) {
        #pragma unroll
        for (int ni = 0; ni < 4; ++ni) {
            int col = n0 + wn + ni * 16 + ln;
            float bb = f ? ((const float*)bias)[col] : bf2f(((const ushort*)bias)[col]);
            #pragma unroll
            for (int r = 0; r < 4; ++r) {
                int row = m0 + wm + mi * 16 + quad * 4 + r;
                float v = acc[mi][ni][r] + bb;
                if (MODE == 0 && f) ((float*)out)[(size_t)row * N + col] = v;
                else                ((ushort*)out)[(size_t)row * N + col] = f2bf(v);
            }
        }
    }
}

// ---------------- GEMM 64x128 (dbuf, one barrier/iter) ----------------
// Used ONLY for the out-proj (N=1024): 512 blocks = 2/CU vs 1/CU at 128-tile;
// B here is 2 MB (L2-resident) so the doubled B-traffic is cheap.
template<int MODE>
__global__ __launch_bounds__(256)
void gemm64(const void* __restrict__ Araw, const ushort* __restrict__ Aconv,
            const ushort* __restrict__ WT, const void* __restrict__ bias,
            void* __restrict__ out, int N, int K, const int* __restrict__ flag)
{
    __shared__ ushort As[2][64 * 32];    // 8 KB
    __shared__ ushort Bs[2][128 * 32];   // 16 KB

    const int f = *flag;
    const ushort* A = (MODE == 1) ? (f ? Aconv : (const ushort*)Araw) : Aconv;

    const int tid = threadIdx.x;
    const int w = tid >> 6, lane = tid & 63;
    const int ln = lane & 15, quad = lane >> 4;
    const int m0 = blockIdx.y * 64, n0 = blockIdx.x * 128;
    const int wn = w * 32;

    const int sa = tid;
    const int arow = sa >> 2, akc = ((sa & 3) ^ ((arow >> 1) & 3)) * 8;
    const size_t aoff = (size_t)(m0 + arow) * K + akc;
    const int sb0 = tid, sb1 = tid + 256;
    const int br0 = sb0 >> 2, bk0 = ((sb0 & 3) ^ ((br0 >> 1) & 3)) * 8;
    const int br1 = sb1 >> 2, bk1 = ((sb1 & 3) ^ ((br1 >> 1) & 3)) * 8;
    const size_t boff0 = (size_t)(n0 + br0) * K + bk0;
    const size_t boff1 = (size_t)(n0 + br1) * K + bk1;

    const int physc = (quad ^ ((ln >> 1) & 3)) * 8;

    f32x4 acc[4][2] = {};

    const int nk = K >> 5;
    int4 a0 = *(const int4*)(A + aoff);
    int4 b0 = *(const int4*)(WT + boff0);
    int4 b1 = *(const int4*)(WT + boff1);
    *(int4*)(As[0] + sa * 8)  = a0;
    *(int4*)(Bs[0] + sb0 * 8) = b0;
    *(int4*)(Bs[0] + sb1 * 8) = b1;
    a0 = *(const int4*)(A + aoff + 32);
    b0 = *(const int4*)(WT + boff0 + 32);
    b1 = *(const int4*)(WT + boff1 + 32);
    __syncthreads();

    for (int kt = 0; kt < nk; ++kt) {
        const int cur = kt & 1;
        if (kt + 1 < nk) {
            *(int4*)(As[1 - cur] + sa * 8)  = a0;
            *(int4*)(Bs[1 - cur] + sb0 * 8) = b0;
            *(int4*)(Bs[1 - cur] + sb1 * 8) = b1;
        }
        if (kt + 2 < nk) {
            const int kc = (kt + 2) * 32;
            a0 = *(const int4*)(A + aoff + kc);
            b0 = *(const int4*)(WT + boff0 + kc);
            b1 = *(const int4*)(WT + boff1 + kc);
        }

        bf16x8 af[4], bf[2];
        #pragma unroll
        for (int t = 0; t < 4; ++t)
            af[t] = *(const bf16x8*)(As[cur] + (t * 16 + ln) * 32 + physc);
        #pragma unroll
        for (int t = 0; t < 2; ++t)
            bf[t] = *(const bf16x8*)(Bs[cur] + (wn + t * 16 + ln) * 32 + physc);
        #pragma unroll
        for (int mi = 0; mi < 4; ++mi)
            #pragma unroll
            for (int ni = 0; ni < 2; ++ni)
                acc[mi][ni] = __builtin_amdgcn_mfma_f32_16x16x32_bf16(
                    af[mi], bf[ni], acc[mi][ni], 0, 0, 0);
        __syncthreads();
    }

    #pragma unroll
    for (int mi = 0; mi < 4; ++mi) {
        #pragma unroll
        for (int ni = 0; ni < 2; ++ni) {
            int col = n0 + wn + ni * 16 + ln;
            float bb = f ? ((const float*)bias)[col] : bf2f(((const ushort*)bias)[col]);
            #pragma unroll
            for (int r = 0; r < 4; ++r) {
                int row = m0 + mi * 16 + quad * 4 + r;
                float v = acc[mi][ni][r] + bb;
                if (MODE == 0 && f) ((float*)out)[(size_t)row * N + col] = v;
                else                ((ushort*)out)[(size_t)row * N + col] = f2bf(v);
            }
        }
    }
}

// ---------------- MFMA flash attention v7 (verbatim: 69.5 us, 3x-replicated) ----------------
__global__ __launch_bounds__(256)
void flash_attn7(const ushort* __restrict__ qkv, ushort* __restrict__ attn)
{
    __shared__ ushort Ks[64][72];
    __shared__ ushort Vs[64][72];
    __shared__ ushort QPs[128][72];  // [pg*64 + mt*32 + local]

    const int tid  = threadIdx.x;          // 256 thr, 4 waves
    const int wave = tid >> 6, lane = tid & 63;
    const int ln   = lane & 15, quad = lane >> 4;
    const int pg   = wave >> 1, ww = wave & 1;
    const int bh   = blockIdx.x;    // all blocks of a bh land on XCD bh%8
    const int ky   = blockIdx.y;
    const int k    = (ky < 8) ? ky : 23 - ky;
    const int xx   = 2 * k + pg;
    const int b    = bh >> 4, hh = bh & (NUM_HEADS - 1);
    const int W3   = 3 * D_MODEL;
    const size_t hbase = (size_t)b * SEQ * W3 + hh * D_K;

    const int q0A = 32 * (63 - xx), q0B = 32 * xx;
    const int ntA = 32 - k, ntB = k + 1;     // identical for both pg

    const int qrr = tid >> 1, qcol = (tid & 1) * 32;       // Q: 128 rows x 64
    const int ksr = tid >> 2, ksc = (tid & 3) * 16;        // K: 64 rows, 2 int4
    const int vp  = tid & 31, vg = (tid >> 5) * 8;         // V: 8 b32 each

    // stage both pairs' Q tiles (128 rows), scaled by 0.125*log2(e)
    {
        const int qpg = qrr >> 6, qmt = (qrr >> 5) & 1, ql = qrr & 31;
        const int qxx = 2 * k + qpg;
        const int grow = qmt ? (32 * qxx + ql) : (32 * (63 - qxx) + ql);
        const ushort* src = qkv + hbase + (size_t)grow * W3 + qcol;
        #pragma unroll
        for (int h = 0; h < 4; ++h) {
            P16 v; v.i4 = *(const int4*)(src + h * 8);
            #pragma unroll
            for (int e = 0; e < 8; ++e) v.u[e] = f2bf(bf2f(v.u[e]) * 0.18033688011f);
            *(int4*)(&QPs[qrr][qcol + h * 8]) = v.i4;
        }
    }
    __syncthreads();
    bf16x8 qf[2][2];
    #pragma unroll
    for (int mt = 0; mt < 2; ++mt)
        #pragma unroll
        for (int s = 0; s < 2; ++s)
            qf[mt][s] = *(const bf16x8*)(&QPs[pg * 64 + mt * 32 + ww * 16 + ln][s * 32 + quad * 8]);

    f32x4 acc_o[2][4] = {};
    f32x4 acc_l[2] = {};

    bf16x8 ones8;
    #pragma unroll
    for (int e = 0; e < 8; ++e) ones8[e] = (short)0x3F80;   // bf16 1.0

    const ushort* Kbase = qkv + hbase + D_MODEL;
    const ushort* Vbase = qkv + hbase + 2 * D_MODEL;

    int4 kreg[2], vreg[2];
    {
        const ushort* ksrc = Kbase + (size_t)ksr * W3 + ksc;
        kreg[0] = *(const int4*)(ksrc);
        kreg[1] = *(const int4*)(ksrc + 8);
        vreg[0] = *(const int4*)(Vbase + (size_t)(2 * vp)     * W3 + vg);
        vreg[1] = *(const int4*)(Vbase + (size_t)(2 * vp + 1) * W3 + vg);
    }

    for (int jt = 0; jt < ntA; ++jt) {
        const int j0 = jt * 64;
        const bool doB = (jt < ntB);
        __syncthreads();

        *(int4*)(&Ks[ksr][ksc])     = kreg[0];
        *(int4*)(&Ks[ksr][ksc + 8]) = kreg[1];
        {
            P16 v0, v1; v0.i4 = vreg[0]; v1.i4 = vreg[1];
            #pragma unroll
            for (int e = 0; e < 8; ++e) {
                unsigned int pack = (unsigned int)v0.u[e] | ((unsigned int)v1.u[e] << 16);
                *(unsigned int*)(&Vs[vg + e][2 * vp]) = pack;
            }
        }
        __syncthreads();

        if (jt + 1 < ntA) {
            const int jn = j0 + 64;
            const ushort* ksrc = Kbase + (size_t)(jn + ksr) * W3 + ksc;
            kreg[0] = *(const int4*)(ksrc);
            kreg[1] = *(const int4*)(ksrc + 8);
            vreg[0] = *(const int4*)(Vbase + (size_t)(jn + 2 * vp)     * W3 + vg);
            vreg[1] = *(const int4*)(Vbase + (size_t)(jn + 2 * vp + 1) * W3 + vg);
        }

        f32x4 sa[2][4];
        #pragma unroll
        for (int t = 0; t < 4; ++t) {
            bf16x8 k0 = *(const bf16x8*)(&Ks[t * 16 + ln][quad * 8]);
            bf16x8 k1 = *(const bf16x8*)(&Ks[t * 16 + ln][32 + quad * 8]);
            {
                f32x4 z = {};
                z = __builtin_amdgcn_mfma_f32_16x16x32_bf16(qf[0][0], k0, z, 0, 0, 0);
                z = __builtin_amdgcn_mfma_f32_16x16x32_bf16(qf[0][1], k1, z, 0, 0, 0);
                sa[0][t] = z;
            }
            if (doB) {
                f32x4 z = {};
                z = __builtin_amdgcn_mfma_f32_16x16x32_bf16(qf[1][0], k0, z, 0, 0, 0);
                z = __builtin_amdgcn_mfma_f32_16x16x32_bf16(qf[1][1], k1, z, 0, 0, 0);
                sa[1][t] = z;
            }
        }

        if (jt == ntA - 1) {
            const int rowb = q0A + ww * 16 + quad * 4;
            #pragma unroll
            for (int t = 0; t < 4; ++t)
                #pragma unroll
                for (int r = 0; r < 4; ++r)
                    if (j0 + t * 16 + ln > rowb + r) sa[0][t][r] = -1e30f;
        }
        if (doB && jt == ntB - 1) {
            const int rowb = q0B + ww * 16 + quad * 4;
            #pragma unroll
            for (int t = 0; t < 4; ++t)
                #pragma unroll
                for (int r = 0; r < 4; ++r)
                    if (j0 + t * 16 + ln > rowb + r) sa[1][t][r] = -1e30f;
        }

        const int lnx = ln ^ ((quad & 1) * 8);
        #pragma unroll
        for (int mt = 0; mt < 2; ++mt) {
            if (mt && !doB) break;
            #pragma unroll
            for (int r = 0; r < 4; ++r) {
                const int prow = pg * 64 + mt * 32 + ww * 16 + quad * 4 + r;
                #pragma unroll
                for (int t = 0; t < 4; ++t) {
                    FU cc; cc.f = exp2f(sa[mt][t][r]);
                    QPs[prow][((t ^ (quad >> 1)) * 16) + lnx] = (ushort)(cc.u >> 16);
                }
            }
        }

        #pragma unroll
        for (int s = 0; s < 2; ++s) {
            const int pcol = s * 32 + ((quad ^ ((ln >> 2) & 3)) * 8);
            bf16x8 pf0 = *(const bf16x8*)(&QPs[pg * 64 + ww * 16 + ln][pcol]);
            bf16x8 pf1;
            if (doB) pf1 = *(const bf16x8*)(&QPs[pg * 64 + 32 + ww * 16 + ln][pcol]);
            #pragma unroll
            for (int t = 0; t < 4; ++t) {
                bf16x8 vf = *(const bf16x8*)(&Vs[t * 16 + ln][s * 32 + quad * 8]);
                acc_o[0][t] = __builtin_amdgcn_mfma_f32_16x16x32_bf16(pf0, vf, acc_o[0][t], 0, 0, 0);
                if (doB)
                    acc_o[1][t] = __builtin_amdgcn_mfma_f32_16x16x32_bf16(pf1, vf, acc_o[1][t], 0, 0, 0);
            }
            acc_l[0] = __builtin_amdgcn_mfma_f32_16x16x32_bf16(pf0, ones8, acc_l[0], 0, 0, 0);
            if (doB)
                acc_l[1] = __builtin_amdgcn_mfma_f32_16x16x32_bf16(pf1, ones8, acc_l[1], 0, 0, 0);
        }
    }

    #pragma unroll
    for (int mt = 0; mt < 2; ++mt) {
        const int q0 = mt ? q0B : q0A;
        #pragma unroll
        for (int r = 0; r < 4; ++r) {
            float inv = 1.0f / acc_l[mt][r];
            int i = q0 + ww * 16 + quad * 4 + r;
            size_t rowoff = ((size_t)(b * SEQ + i)) * D_MODEL + hh * D_K;
            #pragma unroll
            for (int t = 0; t < 4; ++t)
                attn[rowoff + t * 16 + ln] = f2bf(acc_o[mt][t][r] * inv);
        }
    }
}

extern "C" void kernel_launch(void* const* d_in, const int* in_sizes, int n_in,
                              void* d_out, int out_size, void* d_ws, size_t ws_size,
                              hipStream_t stream)
{
    const void* x     = d_in[0];
    // d_in[1] = int32 tril mask -- causal handled analytically
    const void* w_qkv = d_in[2];
    const void* b_qkv = d_in[3];
    const void* w_out = d_in[4];
    const void* b_out = d_in[5];

    char* ws = (char*)d_ws;
    int*    flag   = (int*)ws;                  size_t off = 256;
    ushort* WqkvT  = (ushort*)(ws + off);       off += (size_t)3 * D_MODEL * D_MODEL * 2;
    ushort* WoutT  = (ushort*)(ws + off);       off += (size_t)D_MODEL * D_MODEL * 2;
    ushort* qkv_ws = (ushort*)(ws + off);       off += (size_t)BATCH * SEQ * 3 * D_MODEL * 2;
    ushort* xb     = (ushort*)(ws + off);       // aliases attn_ws: xb dead after QKV gemm
    ushort* attn_ws = xb;

    const int M = BATCH * SEQ;          // 4096

    prep_all<<<3072, 256, 0, stream>>>((const ushort*)x, w_qkv, w_out,
                                       xb, WqkvT, WoutT, flag);

    gemm128<1><<<dim3(3 * D_MODEL / 128, M / 128), 256, 0, stream>>>(
        x, xb, WqkvT, b_qkv, qkv_ws, 3 * D_MODEL, D_MODEL, flag);

    dim3 ga(BATCH * NUM_HEADS, 16);   // x = bh (XCD locality), y = ky
    flash_attn7<<<ga, 256, 0, stream>>>(qkv_ws, attn_ws);

    gemm64<0><<<dim3(D_MODEL / 128, M / 64), 256, 0, stream>>>(
        attn_ws, attn_ws, WoutT, b_out, d_out, D_MODEL, D_MODEL, flag);
}